// Round 4
// baseline (99.831 us; speedup 1.0000x reference)
//
#include <hip/hip_runtime.h>
#include <hip/hip_bf16.h>

#define DIM 384
#define BATCH 1024
#define SPLANE (DIM * DIM)

// f32 -> bf16 bits with round-to-nearest-even (finite inputs only)
__device__ __forceinline__ unsigned tobf(float x) {
    unsigned u = __float_as_uint(x);
    return (u + 0x7fffu + ((u >> 16) & 1u)) >> 16;
}
__device__ __forceinline__ float bflo(unsigned u) {   // low bf16 -> f32
    return __uint_as_float(u << 16);
}
__device__ __forceinline__ float bfhi(unsigned u) {   // high bf16 -> f32
    return __uint_as_float(u & 0xffff0000u);
}

// ---------------------------------------------------------------------------
// Kernel 1: weight prep.
//   Prwp[(i>>1)*DIM + j] = pack_bf16( rw[i]*(1-W0)(1-W1)(1-W2) , row i+1 )
//   qc[j] += sum_i rw[i]*(b0*(1-w1)*(1-w2) + b1*(1-w2) + b2)   (atomics, 64/addr)
// Grid (3, 64) x 128 threads; each thread covers 6 consecutive i for one j.
// ---------------------------------------------------------------------------
__global__ __launch_bounds__(128)
void prep_kernel(const float* __restrict__ W,
                 const float* __restrict__ Bb,
                 const float* __restrict__ rw,
                 unsigned* __restrict__ Prwp,
                 float* __restrict__ qc) {
    const int j  = blockIdx.x * 128 + threadIdx.x;   // 0..DIM-1
    const int i0 = blockIdx.y * 6;                   // even (6*by)
    float s = 0.0f;
    float p[6];
    #pragma unroll
    for (int ii = 0; ii < 6; ++ii) {
        const int i = i0 + ii;
        const int idx = i * DIM + j;
        float w0 = W[idx], w1 = W[SPLANE + idx], w2 = W[2 * SPLANE + idx];
        float b0 = Bb[idx], b1 = Bb[SPLANE + idx], b2 = Bb[2 * SPLANE + idx];
        float r1 = 1.0f - w1, r2 = 1.0f - w2;
        float r = rw[i];
        p[ii] = r * (1.0f - w0) * r1 * r2;
        s += r * (b0 * r1 * r2 + b1 * r2 + b2);
    }
    #pragma unroll
    for (int t = 0; t < 3; ++t) {
        unsigned lo = tobf(p[2 * t]);
        unsigned hi = tobf(p[2 * t + 1]);
        Prwp[(3 * blockIdx.y + t) * DIM + j] = lo | (hi << 16);
    }
    atomicAdd(&qc[j], s);
}

// ---------------------------------------------------------------------------
// Kernel 2: lin_W (DIM x DIM, row-major [n][j]) -> transposed paired bf16:
//   Wtp[(j>>1)*DIM + n] = pack_bf16( linW[n][j], linW[n][j+1] )
// 64x64 LDS tile transpose. Grid (6,6) x 256 threads.
// ---------------------------------------------------------------------------
__global__ __launch_bounds__(256)
void tconv_kernel(const float* __restrict__ Wl,
                  unsigned* __restrict__ Wtp) {
    __shared__ float T[64][65];
    const int n0 = blockIdx.x * 64;
    const int j0 = blockIdx.y * 64;
    const int tid = threadIdx.x;
    const int c  = tid & 63;        // j offset (load) / n offset (store)
    const int r4 = tid >> 6;        // 0..3
    #pragma unroll
    for (int q = 0; q < 16; ++q) {
        int row = r4 + 4 * q;       // n within tile
        T[row][c] = Wl[(n0 + row) * DIM + j0 + c];
    }
    __syncthreads();
    #pragma unroll
    for (int q = 0; q < 8; ++q) {
        int jp = r4 + 4 * q;        // j-pair within tile, 0..31
        unsigned lo = tobf(T[c][2 * jp]);
        unsigned hi = tobf(T[c][2 * jp + 1]);
        Wtp[(j0 / 2 + jp) * DIM + n0 + c] = lo | (hi << 16);
    }
}

// ---------------------------------------------------------------------------
// Kernel 3: fused double-GEMM. One block = 4 batch rows, 384 threads.
//   stage 1: t[r][j]  = sum_k v1[r][k] * Prw[k][j]      (thread = j)
//            pooled   = v2 .* t - qc   -> LDS (transposed [j][r])
//   stage 2: out[r][n] = sum_j pooled[r][j] * linW[n][j] + lb[n]  (thread = n)
// B-matrices stream from L2 as paired bf16 (coalesced dword per 2 k).
// A-operands are wave-uniform broadcast ds_read_b128 from LDS.
// ---------------------------------------------------------------------------
__global__ __launch_bounds__(384)
void fused_kernel(const float* __restrict__ v1,
                  const float* __restrict__ v2,
                  const unsigned* __restrict__ Prwp,
                  const unsigned* __restrict__ Wtp,
                  const float* __restrict__ qc,
                  const float* __restrict__ lb,
                  float* __restrict__ out) {
    __shared__ float AT[DIM][4];   // v1T: [k][r]
    __shared__ float PT[DIM][4];   // pooledT: [j][r]
    const int bm  = blockIdx.x * 4;
    const int tid = threadIdx.x;   // 0..383

    // stage v1 rows bm..bm+3 into AT[k][r]
    {
        const int r  = tid & 3;
        const int kq = tid >> 2;   // 0..95
        float4 a = *(const float4*)&v1[(bm + r) * DIM + 4 * kq];
        AT[4 * kq + 0][r] = a.x;
        AT[4 * kq + 1][r] = a.y;
        AT[4 * kq + 2][r] = a.z;
        AT[4 * kq + 3][r] = a.w;
    }
    __syncthreads();

    // ---- stage 1: thread owns column j = tid ----
    float a0 = 0.f, a1 = 0.f, a2 = 0.f, a3 = 0.f;
    {
        const unsigned* bp = Prwp + tid;
        #pragma unroll 8
        for (int kp = 0; kp < DIM / 2; ++kp) {
            unsigned u = bp[kp * DIM];
            float blo = bflo(u), bhi = bfhi(u);
            float4 va = *(const float4*)&AT[2 * kp][0];
            float4 vb = *(const float4*)&AT[2 * kp + 1][0];
            a0 += va.x * blo + vb.x * bhi;
            a1 += va.y * blo + vb.y * bhi;
            a2 += va.z * blo + vb.z * bhi;
            a3 += va.w * blo + vb.w * bhi;
        }
    }
    // epilogue: pooled = v2 .* t - qc  -> PT[j][r]
    {
        float q = qc[tid];
        float4 pv;
        pv.x = v2[(bm + 0) * DIM + tid] * a0 - q;
        pv.y = v2[(bm + 1) * DIM + tid] * a1 - q;
        pv.z = v2[(bm + 2) * DIM + tid] * a2 - q;
        pv.w = v2[(bm + 3) * DIM + tid] * a3 - q;
        *(float4*)&PT[tid][0] = pv;
    }
    __syncthreads();

    // ---- stage 2: thread owns output column n = tid ----
    float o0 = 0.f, o1 = 0.f, o2 = 0.f, o3 = 0.f;
    {
        const unsigned* wp = Wtp + tid;
        #pragma unroll 8
        for (int jp = 0; jp < DIM / 2; ++jp) {
            unsigned u = wp[jp * DIM];
            float wlo = bflo(u), whi = bfhi(u);
            float4 pa = *(const float4*)&PT[2 * jp][0];
            float4 pb = *(const float4*)&PT[2 * jp + 1][0];
            o0 += pa.x * wlo + pb.x * whi;
            o1 += pa.y * wlo + pb.y * whi;
            o2 += pa.z * wlo + pb.z * whi;
            o3 += pa.w * wlo + pb.w * whi;
        }
    }
    {
        float b = lb[tid];
        out[(bm + 0) * DIM + tid] = o0 + b;
        out[(bm + 1) * DIM + tid] = o1 + b;
        out[(bm + 2) * DIM + tid] = o2 + b;
        out[(bm + 3) * DIM + tid] = o3 + b;
    }
}

extern "C" void kernel_launch(void* const* d_in, const int* in_sizes, int n_in,
                              void* d_out, int out_size, void* d_ws, size_t ws_size,
                              hipStream_t stream) {
    const float* v1  = (const float*)d_in[0];
    const float* v2  = (const float*)d_in[1];
    const float* bW  = (const float*)d_in[2];
    const float* bB  = (const float*)d_in[3];
    const float* rw  = (const float*)d_in[4];
    const float* lW  = (const float*)d_in[5];
    const float* lb  = (const float*)d_in[6];
    float* out = (float*)d_out;

    // workspace layout
    float*    qc   = (float*)d_ws;                       // DIM f32
    unsigned* Prwp = (unsigned*)((char*)d_ws + 4096);    // (DIM/2)*DIM u32 = 288KB
    unsigned* Wtp  = Prwp + (DIM / 2) * DIM;             // 288KB

    hipMemsetAsync(qc, 0, DIM * sizeof(float), stream);

    dim3 gp(DIM / 128, DIM / 6);                 // (3, 64)
    prep_kernel<<<gp, 128, 0, stream>>>(bW, bB, rw, Prwp, qc);

    dim3 gt(DIM / 64, DIM / 64);                 // (6, 6)
    tconv_kernel<<<gt, 256, 0, stream>>>(lW, Wtp);

    fused_kernel<<<BATCH / 4, 384, 0, stream>>>(v1, v2, Prwp, Wtp, qc, lb, out);
}